// Round 12
// baseline (512.079 us; speedup 1.0000x reference)
//
#include <hip/hip_runtime.h>
#include <hip/hip_bf16.h>

#define TOKENS 16384
#define DMODEL 4096
#define NCH 8
#define CH 512
#define BM 96
#define NTILES 171   // ceil(16384/96)

typedef short s16x8 __attribute__((ext_vector_type(8)));
typedef float f32x4 __attribute__((ext_vector_type(4)));

__device__ __forceinline__ unsigned short f2bf(float f) {
    unsigned u = __float_as_uint(f);
    u += 0x7fffu + ((u >> 16) & 1u);
    return (unsigned short)(u >> 16);
}

// tanh-form GELU via single v_exp
__device__ __forceinline__ float gelu_fast(float x) {
    float u = 1.5957691216057308f * x * (1.0f + 0.044715f * x * x);
    float e = __expf(u);
    return x - x * __builtin_amdgcn_rcpf(e + 1.0f);
}

// ---------------------------------------------------------------------------
// K0: weight prep into MFMA-fragment-packed layout (unchanged).
// P[n][kt*32+nb][lane][8]: 1KB contiguous per (kt,nb) line.
// ---------------------------------------------------------------------------
__global__ __launch_bounds__(256)
void wprep_kernel(const float* __restrict__ w1, const float* __restrict__ w2,
                  unsigned short* __restrict__ p1, unsigned short* __restrict__ p2)
{
    const int lane = threadIdx.x;
    const int sub  = threadIdx.y;
    const int kt   = blockIdx.x;
    const int nb   = blockIdx.y * 4 + sub;
    const int which = blockIdx.z >> 3;
    const int n     = blockIdx.z & 7;

    const int kg  = lane >> 4;
    const int l15 = lane & 15;

    const float* src = (which ? w2 : w1) + (size_t)n * CH * CH;
    unsigned short* dst = (which ? p2 : p1) + (size_t)n * CH * CH
                        + ((size_t)(kt * 32 + nb) * 64 + lane) * 8;

    unsigned short v[8];
#pragma unroll
    for (int j = 0; j < 8; ++j)
        v[j] = f2bf(src[(size_t)(kt * 32 + kg * 8 + j) * CH + nb * 16 + l15]);

    uint4 q;
    q.x = (unsigned)v[0] | ((unsigned)v[1] << 16);
    q.y = (unsigned)v[2] | ((unsigned)v[3] << 16);
    q.z = (unsigned)v[4] | ((unsigned)v[5] << 16);
    q.w = (unsigned)v[6] | ((unsigned)v[7] << 16);
    *(uint4*)dst = q;
}

// ---------------------------------------------------------------------------
// K1: fused chunk MLP, BM=96. 8 waves: wg=wid>>2 (M half: 48 rows),
// wn=wid&3 (N slice: 128 cols). acc[3][8].
// LDS: [0,96K) Xc/H1 bf16 XOR-swizzled (aliased); [96K,128K) B buf0;
// [128K,160K) B buf1  => 160 KB exactly.
// Per kt: stage(kt+1) -> s_waitcnt vmcnt(4) -> s_barrier -> ds_read+24 MFMA.
// Counted vmcnt keeps next stage in flight across the barrier (T3/T4-min);
// setprio around MFMA cluster (T5, now phase-structured).
// ---------------------------------------------------------------------------
#define XC_BYTES (BM * CH * 2)            // 98304
#define BBUF(i)  (XC_BYTES + (i) * 32768)

__global__ __launch_bounds__(512, 1)
void mlp_kernel(const float* __restrict__ x,
                const unsigned short* __restrict__ p1,
                const unsigned short* __restrict__ p2,
                const float* __restrict__ b1,
                const float* __restrict__ b2,
                float* __restrict__ mid)
{
    __shared__ unsigned char lds[XC_BYTES + 2 * 32768];   // 160 KB
    const int tile = blockIdx.x;
    const int n    = blockIdx.y;
    const int tid  = threadIdx.x;
    const int wid  = tid >> 6;
    const int lane = tid & 63;
    const int row0 = tile * BM;
    const int kt0  = (tile >> 3) & 15;    // herd-breaker K rotation

    const int wg = wid >> 2;              // 0,1: rows wg*48..+47
    const int wn = wid & 3;               // 0..3: cols wn*128..+127
    const int l15 = lane & 15;
    const int kg  = lane >> 4;

    const unsigned short* p1n = p1 + (size_t)n * CH * CH;
    const unsigned short* p2n = p2 + (size_t)n * CH * CH;

    // biases first (drained by prologue barrier)
    float b1v[8], b2v[8];
#pragma unroll
    for (int ni = 0; ni < 8; ++ni) {
        int col = n * CH + wn * 128 + ni * 16 + l15;
        b1v[ni] = b1[col];
        b2v[ni] = b2[col];
    }

    // wave stages lines wid*4..+3 (4 x 1KB) of physical k-tile kt into bufb
    auto stageB = [&](const unsigned short* pk, int kt, int bufb) {
#pragma unroll
        for (int i = 0; i < 4; ++i) {
            const unsigned short* src = pk + ((size_t)(kt * 32 + wid * 4 + i) * 64 + lane) * 8;
            unsigned char* dstp = lds + bufb + (wid * 4 + i) * 1024;  // wave-uniform
            __builtin_amdgcn_global_load_lds(
                (const __attribute__((address_space(1))) void*)src,
                (__attribute__((address_space(3))) void*)dstp,
                16, 0, 0);
        }
    };

    // ---- prologue: issue stage(0)->buf0, then Xc (fp32->bf16, swizzled, guarded)
    stageB(p1n, kt0, BBUF(0));
    {
        const float* xc = x + (size_t)row0 * DMODEL + n * CH;
#pragma unroll
        for (int it = 0; it < 24; ++it) {
            int f = it * 512 + tid;        // float4 index: 128 per row, 96 rows
            int r = f >> 7;
            int c = (f & 127) << 2;
            float4 v = make_float4(0.f, 0.f, 0.f, 0.f);
            if (row0 + r < TOKENS)
                v = *(const float4*)(xc + (size_t)r * DMODEL + c);
            unsigned lo = (unsigned)f2bf(v.x) | ((unsigned)f2bf(v.y) << 16);
            unsigned hi = (unsigned)f2bf(v.z) | ((unsigned)f2bf(v.w) << 16);
            int byte = ((r * CH + c) * 2) ^ ((r & 7) << 4);
            *(uint2*)(lds + byte) = make_uint2(lo, hi);
        }
    }
    __syncthreads();   // drains stage(0) + biases (vm) and Xc writes (lgkm)

    f32x4 acc[3][8];
    auto zacc = [&]() {
#pragma unroll
        for (int mi = 0; mi < 3; ++mi)
#pragma unroll
            for (int ni = 0; ni < 8; ++ni)
                acc[mi][ni] = (f32x4){0.f, 0.f, 0.f, 0.f};
    };

    // one kt compute: 3 A-frags (Xc/H1 at physical kt) + 8 B-frags, 24 MFMA
    auto step = [&](int ktp, int bufb) {
        s16x8 a[3], b[8];
#pragma unroll
        for (int mi = 0; mi < 3; ++mi) {
            int r = wg * 48 + mi * 16 + l15;
            int byte = ((r * CH + ktp * 32 + kg * 8) * 2) ^ ((r & 7) << 4);
            a[mi] = *(const s16x8*)(lds + byte);
        }
#pragma unroll
        for (int ni = 0; ni < 8; ++ni)
            b[ni] = *(const s16x8*)(lds + bufb + ((wn * 8 + ni) * 64 + lane) * 16);
        __builtin_amdgcn_s_setprio(1);
#pragma unroll
        for (int ni = 0; ni < 8; ++ni)
#pragma unroll
            for (int mi = 0; mi < 3; ++mi)
                acc[mi][ni] = __builtin_amdgcn_mfma_f32_16x16x32_bf16(
                    a[mi], b[ni], acc[mi][ni], 0, 0, 0);
        __builtin_amdgcn_s_setprio(0);
    };

    // ================= GEMM1: c = 0..15 =================
    zacc();
#pragma unroll 1
    for (int c = 0; c < 16; ++c) {
        if (c < 15) stageB(p1n, (c + 1 + kt0) & 15, BBUF((c + 1) & 1));
        else        stageB(p2n, kt0,                BBUF(0));     // stage(16)
        asm volatile("s_waitcnt vmcnt(4)" ::: "memory");          // stage(c) landed
        __builtin_amdgcn_s_barrier();                             // all waves' stage(c) landed
        step((c + kt0) & 15, BBUF(c & 1));
    }

    // transition: all waves' Xc reads retired (MFMA consumption forced lgkm
    // drain before each wave reached the last barrier-equivalent point)
    __builtin_amdgcn_s_barrier();

    // bias1 + GELU -> H1 bf16 into (aliased) LDS region, same swizzle
#pragma unroll
    for (int mi = 0; mi < 3; ++mi)
#pragma unroll
        for (int ni = 0; ni < 8; ++ni)
#pragma unroll
            for (int r = 0; r < 4; ++r) {
                float v = gelu_fast(acc[mi][ni][r] + b1v[ni]);
                int row  = wg * 48 + mi * 16 + kg * 4 + r;
                int col  = wn * 128 + ni * 16 + l15;
                int byte = ((row * CH + col) * 2) ^ ((row & 7) << 4);
                *(unsigned short*)(lds + byte) = f2bf(v);
            }
    asm volatile("s_waitcnt lgkmcnt(0)" ::: "memory");   // H1 writes committed
    __builtin_amdgcn_s_barrier();                        // H1 visible to all

    // ================= GEMM2: cl = 0..15 (stage(16) already in flight) =====
    zacc();
#pragma unroll 1
    for (int cl = 0; cl < 16; ++cl) {
        if (cl < 15) {
            stageB(p2n, (cl + 1 + kt0) & 15, BBUF((cl + 1) & 1));
            asm volatile("s_waitcnt vmcnt(4)" ::: "memory");
        } else {
            asm volatile("s_waitcnt vmcnt(0)" ::: "memory");
        }
        __builtin_amdgcn_s_barrier();
        step((cl + kt0) & 15, BBUF(cl & 1));
    }

    // ---- epilogue: + b2 + residual x, store fp32 pre-LN (guarded tail) ----
    const float* xr = x   + (size_t)row0 * DMODEL + n * CH;
    float*       mr = mid + (size_t)row0 * DMODEL + n * CH;
#pragma unroll
    for (int mi = 0; mi < 3; ++mi)
#pragma unroll
        for (int ni = 0; ni < 8; ++ni)
#pragma unroll
            for (int r = 0; r < 4; ++r) {
                int row = wg * 48 + mi * 16 + kg * 4 + r;
                int col = wn * 128 + ni * 16 + l15;
                if (row0 + row < TOKENS) {
                    float v = acc[mi][ni][r] + b2v[ni] + xr[(size_t)row * DMODEL + col];
                    mr[(size_t)row * DMODEL + col] = v;
                }
            }
}

// ---------------------------------------------------------------------------
// K2: in-place LayerNorm over rows of `out`.
// ---------------------------------------------------------------------------
__global__ __launch_bounds__(256)
void ln_kernel(float* __restrict__ out,
               const float* __restrict__ g,
               const float* __restrict__ bt)
{
    __shared__ float red[8];
    const int row = blockIdx.x;
    const int tid = threadIdx.x;
    float* p = out + (size_t)row * DMODEL;

    float4 v[4];
    float s = 0.f, ss = 0.f;
#pragma unroll
    for (int i = 0; i < 4; ++i) {
        v[i] = *(const float4*)(p + (i * 256 + tid) * 4);
        s  += v[i].x + v[i].y + v[i].z + v[i].w;
        ss += v[i].x * v[i].x + v[i].y * v[i].y + v[i].z * v[i].z + v[i].w * v[i].w;
    }
#pragma unroll
    for (int o = 32; o > 0; o >>= 1) {
        s  += __shfl_xor(s, o, 64);
        ss += __shfl_xor(ss, o, 64);
    }
    const int wid = tid >> 6, lane = tid & 63;
    if (lane == 0) { red[wid] = s; red[4 + wid] = ss; }
    __syncthreads();
    s  = red[0] + red[1] + red[2] + red[3];
    ss = red[4] + red[5] + red[6] + red[7];
    const float mu   = s * (1.f / DMODEL);
    const float var  = ss * (1.f / DMODEL) - mu * mu;
    const float rstd = rsqrtf(var + 1e-5f);

#pragma unroll
    for (int i = 0; i < 4; ++i) {
        int c = (i * 256 + tid) * 4;
        float4 gv = *(const float4*)(g + c);
        float4 bv = *(const float4*)(bt + c);
        float4 o;
        o.x = (v[i].x - mu) * rstd * gv.x + bv.x;
        o.y = (v[i].y - mu) * rstd * gv.y + bv.y;
        o.z = (v[i].z - mu) * rstd * gv.z + bv.z;
        o.w = (v[i].w - mu) * rstd * gv.w + bv.w;
        *(float4*)(p + c) = o;
    }
}

// ---------------------------------------------------------------------------
extern "C" void kernel_launch(void* const* d_in, const int* in_sizes, int n_in,
                              void* d_out, int out_size, void* d_ws, size_t ws_size,
                              hipStream_t stream)
{
    const float* x    = (const float*)d_in[0];
    const float* w1   = (const float*)d_in[1];
    const float* b1   = (const float*)d_in[2];
    const float* w2   = (const float*)d_in[3];
    const float* b2   = (const float*)d_in[4];
    const float* ln_g = (const float*)d_in[5];
    const float* ln_b = (const float*)d_in[6];
    float* out = (float*)d_out;

    unsigned short* p1 = (unsigned short*)d_ws;           // 4 MiB packed W1
    unsigned short* p2 = p1 + (size_t)NCH * CH * CH;      // 4 MiB packed W2

    wprep_kernel<<<dim3(16, 8, 16), dim3(64, 4), 0, stream>>>(w1, w2, p1, p2);
    mlp_kernel<<<dim3(NTILES, NCH), dim3(512), 0, stream>>>(x, p1, p2, b1, b2, out);
    ln_kernel<<<dim3(TOKENS), dim3(256), 0, stream>>>(out, ln_g, ln_b);
}